// Round 1
// baseline (187.537 us; speedup 1.0000x reference)
//
#include <hip/hip_runtime.h>
#include <hip/hip_bf16.h>
#include <math.h>

// BilinearGate fused. B=8, Cin=256, HW=9216, R=32, TRI=528, Cout=256.
// v2: 512-thread blocks (8 waves), 64 px/block, 1152 blocks.
// Per-wave GEMM2 tile cut 64x64 -> 32x64 (acc 64->32 regs) so total unified
// VGPR+AGPR fits <=128 -> 4 waves/SIMD -> 16 waves/CU (was ~8, reg-capped).
// Phase 1: each wave computes one 16x16 out-tile (mt=wv>>2 row-half,
//   nt=wv&3 px-quarter), split-fp16 3-term MFMA; waves sharing a px-quarter
//   duplicate x loads (16KB quarter -> L1-resident).
// up-build: 8 waves split each half (288 t: 36/wave; 256 t: 32/wave) with
//   COMPILE-TIME triu indices, f16x4 stores.
// Phase 2: per half, chunks of K=32, A direct from global (L2-resident w16),
//   B from LDS b128, 8 MFMA/chunk/wave. 5 barriers total.
#define HW     9216
#define CIN    256
#define RCH    32
#define NTRI   528
#define COUT   256
#define NB     8
#define W16ROW 544   // fp16 w_recover row: 17*32, zero-padded past 528
#define UPROW  296   // halfs per upS row (288 data + 8 pad) = 592 B

typedef _Float16 f16x8 __attribute__((ext_vector_type(8)));
typedef _Float16 f16x4 __attribute__((ext_vector_type(4)));
typedef float    f32x4 __attribute__((ext_vector_type(4)));

struct TriTab { unsigned char i[544]; unsigned char j[544]; };
constexpr TriTab make_tri() {
  TriTab t{};
  int ii = 0, jj = 0;
  for (int k = 0; k < 544; ++k) {
    if (k < NTRI) {
      t.i[k] = (unsigned char)ii; t.j[k] = (unsigned char)jj;
      if (++jj == 32) { ++ii; jj = ii; }
    } else { t.i[k] = 0; t.j[k] = 0; }
  }
  return t;
}
constexpr TriTab TRI = make_tri();

// Wave TQ (0..7) builds its share of up[p][t] for one half.
// HALF 0: t in [TQ*36, TQ*36+36), 9 f16x4 groups.
// HALF 1: t in [288+TQ*32, 288+TQ*32+32), 8 f16x4 groups.
// All indices compile-time -> o[] statically indexed, t>=528 folds to 0.
template<int TQ, int HALF>
__device__ __forceinline__ void build_up(const float (&o)[RCH], _Float16* rowp) {
  constexpr int NG  = HALF ? 8 : 9;
  constexpr int TLB = TQ * (HALF ? 32 : 36);   // local t base (x2B is 8B-mult)
  constexpr int TB  = HALF ? 288 : 0;          // global t base
#pragma unroll
  for (int g = 0; g < NG; ++g) {
    f16x4 v;
#pragma unroll
    for (int s = 0; s < 4; ++s) {
      const int tl = TLB + g * 4 + s;
      const int t  = TB + tl;
      float f = (t < NTRI) ? o[TRI.i[t]] * o[TRI.j[t]] : 0.0f;
      v[s] = (_Float16)f;
    }
    *(f16x4*)&rowp[TLB + g * 4] = v;
  }
}

template<int HALF>
__device__ __forceinline__ void build_dispatch(int wv, const float (&o)[RCH],
                                               _Float16* rowp) {
  switch (wv) {
    case 0: build_up<0, HALF>(o, rowp); break;
    case 1: build_up<1, HALF>(o, rowp); break;
    case 2: build_up<2, HALF>(o, rowp); break;
    case 3: build_up<3, HALF>(o, rowp); break;
    case 4: build_up<4, HALF>(o, rowp); break;
    case 5: build_up<5, HALF>(o, rowp); break;
    case 6: build_up<6, HALF>(o, rowp); break;
    default: build_up<7, HALF>(o, rowp); break;
  }
}

__global__ __launch_bounds__(256) void convert_kernel(
    const float* __restrict__ w_reduce, const float* __restrict__ w_recover,
    _Float16* __restrict__ w16, _Float16* __restrict__ wr16h,
    _Float16* __restrict__ wr16l) {
  const int bx = blockIdx.x;
  const int tid = threadIdx.x;
  if (bx < COUT) {
    for (int t = tid; t < W16ROW; t += 256) {
      float f = (t < NTRI) ? w_recover[(size_t)bx * NTRI + t] : 0.0f;
      w16[(size_t)bx * W16ROW + t] = (_Float16)f;
    }
  } else {
    int e = (bx - COUT) * 512 + tid;
#pragma unroll
    for (int k = 0; k < 2; ++k, e += 256) {
      float f = w_reduce[e];
      _Float16 h = (_Float16)f;
      wr16h[e] = h;
      wr16l[e] = (_Float16)(f - (float)h);
    }
  }
}

__global__ __launch_bounds__(512, 4) void fused_kernel(
    const float* __restrict__ x, const _Float16* __restrict__ w16,
    const _Float16* __restrict__ wr16h, const _Float16* __restrict__ wr16l,
    float* __restrict__ y) {
  __shared__ float outS[RCH * 68];                     // 8.7 KB
  __shared__ __align__(16) _Float16 upS[64 * UPROW];   // 37.9 KB

  const int tid  = threadIdx.x;
  const int bx   = blockIdx.x;          // 1152 = 8 b * 144 px-tiles
  const int b    = bx / 144;
  const int p0   = (bx - b * 144) * 64;
  const int wv   = tid >> 6;
  const int lane = tid & 63;
  const int ml   = lane & 15;
  const int q    = lane >> 4;
  const int mt   = wv >> 2;             // phase-1 out-row half (0..1)
  const int nt   = wv & 3;              // phase-1 px quarter (0..3)

  // ---------------- Phase 1: GEMM1, no LDS, no barriers -------------------
  // Wave wv owns the 16x16 tile rows mt*16..+16, px nt*16..+16.
  {
    f32x4 g1acc;
#pragma unroll
    for (int r2 = 0; r2 < 4; ++r2) g1acc[r2] = 0.0f;

    const float* xb = x + (size_t)b * CIN * HW + p0 + nt * 16 + ml;
#pragma unroll
    for (int ch = 0; ch < 8; ++ch) {
      const int c0 = ch * 32;
      float xv[8];
#pragma unroll
      for (int s = 0; s < 8; ++s)
        xv[s] = xb[(size_t)(c0 + q * 8 + s) * HW];
      f16x8 bh, bl;
#pragma unroll
      for (int s = 0; s < 8; ++s) {
        _Float16 h = (_Float16)xv[s];
        bh[s] = h;
        bl[s] = (_Float16)(xv[s] - (float)h);
      }
      const int off = (mt * 16 + ml) * CIN + c0 + q * 8;
      f16x8 ah = *(const f16x8*)&wr16h[off];
      f16x8 al = *(const f16x8*)&wr16l[off];
      g1acc = __builtin_amdgcn_mfma_f32_16x16x32_f16(ah, bh, g1acc, 0, 0, 0);
      g1acc = __builtin_amdgcn_mfma_f32_16x16x32_f16(al, bh, g1acc, 0, 0, 0);
      g1acc = __builtin_amdgcn_mfma_f32_16x16x32_f16(ah, bl, g1acc, 0, 0, 0);
    }
    // D[row=q*4+reg][col=ml]: r = mt*16+q*4+reg, p = nt*16+ml
#pragma unroll
    for (int reg = 0; reg < 4; ++reg)
      outS[(mt * 16 + q * 4 + reg) * 68 + nt * 16 + ml] = g1acc[reg];
  }
  __syncthreads();   // barrier 1: outS complete

  f32x4 acc[2][4];
#pragma unroll
  for (int mi = 0; mi < 2; ++mi)
#pragma unroll
    for (int ni = 0; ni < 4; ++ni)
#pragma unroll
      for (int r2 = 0; r2 < 4; ++r2) acc[mi][ni][r2] = 0.0f;

  _Float16* rowp = &upS[lane * UPROW];

  // ---------------- HALF 0: build t[0,288) then free-run chunks 0..8 ------
  {
    float o[RCH];
#pragma unroll
    for (int r = 0; r < RCH; ++r) o[r] = outS[r * 68 + lane];  // 2-way, free
    build_dispatch<0>(wv, o, rowp);
  }
  __syncthreads();   // barrier 2: upS half0 ready
#pragma unroll
  for (int c = 0; c < 9; ++c) {
    const int t0 = c * 32;
    f16x8 afr[2];
#pragma unroll
    for (int mi = 0; mi < 2; ++mi)
      afr[mi] = *(const f16x8*)&w16[(size_t)(wv * 32 + mi * 16 + ml) * W16ROW + t0 + q * 8];
    f16x8 bfr[4];
#pragma unroll
    for (int ni = 0; ni < 4; ++ni)
      bfr[ni] = *(const f16x8*)&upS[(ni * 16 + ml) * UPROW + t0 + q * 8];
#pragma unroll
    for (int mi = 0; mi < 2; ++mi)
#pragma unroll
      for (int ni = 0; ni < 4; ++ni)
        acc[mi][ni] = __builtin_amdgcn_mfma_f32_16x16x32_f16(afr[mi], bfr[ni], acc[mi][ni], 0, 0, 0);
  }
  __syncthreads();   // barrier 3: half0 reads done (WAR before overwrite)

  // ---------------- HALF 1: build t[288,544) then free-run chunks 0..7 ----
  {
    float o[RCH];
#pragma unroll
    for (int r = 0; r < RCH; ++r) o[r] = outS[r * 68 + lane];
    build_dispatch<1>(wv, o, rowp);
  }
  __syncthreads();   // barrier 4: upS half1 ready
#pragma unroll
  for (int c = 0; c < 8; ++c) {
    const int t0l = c * 32;          // local offset in upS
    const int t0g = 288 + c * 32;    // global t for w16
    f16x8 afr[2];
#pragma unroll
    for (int mi = 0; mi < 2; ++mi)
      afr[mi] = *(const f16x8*)&w16[(size_t)(wv * 32 + mi * 16 + ml) * W16ROW + t0g + q * 8];
    f16x8 bfr[4];
#pragma unroll
    for (int ni = 0; ni < 4; ++ni)
      bfr[ni] = *(const f16x8*)&upS[(ni * 16 + ml) * UPROW + t0l + q * 8];
#pragma unroll
    for (int mi = 0; mi < 2; ++mi)
#pragma unroll
      for (int ni = 0; ni < 4; ++ni)
        acc[mi][ni] = __builtin_amdgcn_mfma_f32_16x16x32_f16(afr[mi], bfr[ni], acc[mi][ni], 0, 0, 0);
  }

  // ---------------- Epilogue: signed sqrt, dword stores -------------------
#pragma unroll
  for (int mi = 0; mi < 2; ++mi) {
#pragma unroll
    for (int reg = 0; reg < 4; ++reg) {
      const int o = wv * 32 + mi * 16 + q * 4 + reg;
      float* yrow = y + ((size_t)(b * COUT + o)) * HW + p0 + ml;
#pragma unroll
      for (int ni = 0; ni < 4; ++ni) {
        float v = acc[mi][ni][reg];
        float s = sqrtf(fabsf(v) + 1e-6f);
        yrow[ni * 16] = v > 0.0f ? s : (v < 0.0f ? -s : 0.0f);
      }
    }
  }
}

extern "C" void kernel_launch(void* const* d_in, const int* in_sizes, int n_in,
                              void* d_out, int out_size, void* d_ws, size_t ws_size,
                              hipStream_t stream) {
  const float* x         = (const float*)d_in[0];
  const float* w_reduce  = (const float*)d_in[1];
  const float* w_recover = (const float*)d_in[2];
  float* y = (float*)d_out;

  _Float16* w16   = (_Float16*)d_ws;                            // 256*544*2 = 278528 B
  _Float16* wr16h = (_Float16*)((char*)d_ws + 278528);          // 16384 B
  _Float16* wr16l = (_Float16*)((char*)d_ws + 278528 + 16384);  // 16384 B

  convert_kernel<<<COUT + 16, 256, 0, stream>>>(w_reduce, w_recover, w16, wr16h, wr16l);
  fused_kernel<<<NB * (HW / 64), 512, 0, stream>>>(x, w16, wr16h, wr16l, y);
}

// Round 2
// 176.595 us; speedup vs baseline: 1.0620x; 1.0620x over previous
//
#include <hip/hip_runtime.h>
#include <hip/hip_bf16.h>
#include <math.h>

// BilinearGate fused. B=8, Cin=256, HW=9216, R=32, TRI=528, Cout=256.
// v3: latency-chain attack. 512-thread blocks (8 waves), 64 px/block.
// - Phase 1: ALL 64 strided x loads hoisted before conversion -> 1 latency
//   round instead of 8 serial rounds (compiler had VGPR=40, couldn't pipeline).
// - w16 pre-swizzled into MFMA-fragment order (272 rows x 512 halfs, lane-
//   coalesced): afr load = base + c*1KB, trivially pipelinable.
// - Phase 2: explicit depth-1 double-buffer prefetch for afr (global) and
//   bfr (LDS); chunk-0 afr issued before build0/barriers; chunk-9 afr issued
//   before the half0->half1 barriers (loads in flight across barriers).
#define HW     9216
#define CIN    256
#define RCH    32
#define NTRI   528
#define COUT   256
#define NB     8
#define WFROWS 272   // 8 wv * 2 mi * 17 c fragment-rows of 512 halfs
#define UPROW  296   // halfs per upS row (288 data + 8 pad) = 592 B

typedef _Float16 f16x8 __attribute__((ext_vector_type(8)));
typedef _Float16 f16x4 __attribute__((ext_vector_type(4)));
typedef float    f32x4 __attribute__((ext_vector_type(4)));

struct TriTab { unsigned char i[544]; unsigned char j[544]; };
constexpr TriTab make_tri() {
  TriTab t{};
  int ii = 0, jj = 0;
  for (int k = 0; k < 544; ++k) {
    if (k < NTRI) {
      t.i[k] = (unsigned char)ii; t.j[k] = (unsigned char)jj;
      if (++jj == 32) { ++ii; jj = ii; }
    } else { t.i[k] = 0; t.j[k] = 0; }
  }
  return t;
}
constexpr TriTab TRI = make_tri();

// Wave TQ (0..7) builds its share of up[p][t] for one half.
// HALF 0: t in [TQ*36, TQ*36+36). HALF 1: t in [288+TQ*32, 288+TQ*32+32).
// All indices compile-time -> o[] statically indexed, t>=528 folds to 0.
template<int TQ, int HALF>
__device__ __forceinline__ void build_up(const float (&o)[RCH], _Float16* rowp) {
  constexpr int NG  = HALF ? 8 : 9;
  constexpr int TLB = TQ * (HALF ? 32 : 36);   // local t base (x2B is 8B-mult)
  constexpr int TB  = HALF ? 288 : 0;          // global t base
#pragma unroll
  for (int g = 0; g < NG; ++g) {
    f16x4 v;
#pragma unroll
    for (int s = 0; s < 4; ++s) {
      const int tl = TLB + g * 4 + s;
      const int t  = TB + tl;
      float f = (t < NTRI) ? o[TRI.i[t]] * o[TRI.j[t]] : 0.0f;
      v[s] = (_Float16)f;
    }
    *(f16x4*)&rowp[TLB + g * 4] = v;
  }
}

template<int HALF>
__device__ __forceinline__ void build_dispatch(int wv, const float (&o)[RCH],
                                               _Float16* rowp) {
  switch (wv) {
    case 0: build_up<0, HALF>(o, rowp); break;
    case 1: build_up<1, HALF>(o, rowp); break;
    case 2: build_up<2, HALF>(o, rowp); break;
    case 3: build_up<3, HALF>(o, rowp); break;
    case 4: build_up<4, HALF>(o, rowp); break;
    case 5: build_up<5, HALF>(o, rowp); break;
    case 6: build_up<6, HALF>(o, rowp); break;
    default: build_up<7, HALF>(o, rowp); break;
  }
}

// w16 fragment layout: element (((wv*2+mi)*17 + c)*64 + lane)*8 + s holds
// w_recover[o][t] with o = wv*32+mi*16+(lane&15), t = c*32+(lane>>4)*8+s
// (zero-padded for t >= 528). Consumer afr load is 64 lanes x 16 B contiguous.
__global__ __launch_bounds__(256) void convert_kernel(
    const float* __restrict__ w_reduce, const float* __restrict__ w_recover,
    _Float16* __restrict__ w16, _Float16* __restrict__ wr16h,
    _Float16* __restrict__ wr16l) {
  const int bx = blockIdx.x;
  const int tid = threadIdx.x;
  if (bx < WFROWS) {
    const int wv  = bx / 34;
    const int rem = bx - wv * 34;
    const int mi  = rem / 17;
    const int c   = rem - mi * 17;
    const int lane = tid >> 2;           // 0..63
    const int s0   = (tid & 3) * 2;      // 0,2,4,6
    const int o = wv * 32 + mi * 16 + (lane & 15);
    const int t = c * 32 + (lane >> 4) * 8 + s0;
    float f0 = (t     < NTRI) ? w_recover[(size_t)o * NTRI + t]     : 0.0f;
    float f1 = (t + 1 < NTRI) ? w_recover[(size_t)o * NTRI + t + 1] : 0.0f;
    _Float16* p = &w16[((size_t)bx * 64 + lane) * 8 + s0];
    p[0] = (_Float16)f0;
    p[1] = (_Float16)f1;
  } else {
    int e = (bx - WFROWS) * 512 + tid;
#pragma unroll
    for (int k = 0; k < 2; ++k, e += 256) {
      float f = w_reduce[e];
      _Float16 h = (_Float16)f;
      wr16h[e] = h;
      wr16l[e] = (_Float16)(f - (float)h);
    }
  }
}

__global__ __launch_bounds__(512, 4) void fused_kernel(
    const float* __restrict__ x, const _Float16* __restrict__ w16,
    const _Float16* __restrict__ wr16h, const _Float16* __restrict__ wr16l,
    float* __restrict__ y) {
  __shared__ float outS[RCH * 68];                     // 8.7 KB
  __shared__ __align__(16) _Float16 upS[64 * UPROW];   // 37.9 KB

  const int tid  = threadIdx.x;
  const int bx   = blockIdx.x;          // 1152 = 8 b * 144 px-tiles
  const int b    = bx / 144;
  const int p0   = (bx - b * 144) * 64;
  const int wv   = tid >> 6;
  const int lane = tid & 63;
  const int ml   = lane & 15;
  const int q    = lane >> 4;
  const int mt   = wv >> 2;             // phase-1 out-row half (0..1)
  const int nt   = wv & 3;              // phase-1 px quarter (0..3)

  // ---------------- Phase 1: GEMM1, no LDS, no barriers -------------------
  // Wave wv owns the 16x16 tile rows mt*16..+16, px nt*16..+16.
  // All 64 strided x loads issued up front -> one latency round.
  {
    f32x4 g1acc;
#pragma unroll
    for (int r2 = 0; r2 < 4; ++r2) g1acc[r2] = 0.0f;

    const float* xb = x + (size_t)b * CIN * HW + p0 + nt * 16 + ml;
    float xv[64];
#pragma unroll
    for (int ch = 0; ch < 8; ++ch)
#pragma unroll
      for (int s = 0; s < 8; ++s)
        xv[ch * 8 + s] = xb[(size_t)(ch * 32 + q * 8 + s) * HW];

#pragma unroll
    for (int ch = 0; ch < 8; ++ch) {
      f16x8 bh, bl;
#pragma unroll
      for (int s = 0; s < 8; ++s) {
        float f = xv[ch * 8 + s];
        _Float16 h = (_Float16)f;
        bh[s] = h;
        bl[s] = (_Float16)(f - (float)h);
      }
      const int off = (mt * 16 + ml) * CIN + ch * 32 + q * 8;
      f16x8 ah = *(const f16x8*)&wr16h[off];
      f16x8 al = *(const f16x8*)&wr16l[off];
      g1acc = __builtin_amdgcn_mfma_f32_16x16x32_f16(ah, bh, g1acc, 0, 0, 0);
      g1acc = __builtin_amdgcn_mfma_f32_16x16x32_f16(al, bh, g1acc, 0, 0, 0);
      g1acc = __builtin_amdgcn_mfma_f32_16x16x32_f16(ah, bl, g1acc, 0, 0, 0);
    }
    // D[row=q*4+reg][col=ml]: r = mt*16+q*4+reg, p = nt*16+ml
#pragma unroll
    for (int reg = 0; reg < 4; ++reg)
      outS[(mt * 16 + q * 4 + reg) * 68 + nt * 16 + ml] = g1acc[reg];
  }

  // Fragment bases into pre-swizzled w16 (chunk c at +c*512 halfs).
  const _Float16* wf0 = w16 + ((size_t)(wv * 2 + 0) * 17 * 64 + lane) * 8;
  const _Float16* wf1 = w16 + ((size_t)(wv * 2 + 1) * 17 * 64 + lane) * 8;

  // Chunk-0 afr issued BEFORE the barriers/build: in flight across them.
  f16x8 abuf[2][2];
  abuf[0][0] = *(const f16x8*)&wf0[0];
  abuf[0][1] = *(const f16x8*)&wf1[0];

  __syncthreads();   // barrier 1: outS complete

  f32x4 acc[2][4];
#pragma unroll
  for (int mi = 0; mi < 2; ++mi)
#pragma unroll
    for (int ni = 0; ni < 4; ++ni)
#pragma unroll
      for (int r2 = 0; r2 < 4; ++r2) acc[mi][ni][r2] = 0.0f;

  _Float16* rowp = &upS[lane * UPROW];

  // ---------------- HALF 0: build t[0,288) then chunks c=0..8 -------------
  {
    float o[RCH];
#pragma unroll
    for (int r = 0; r < RCH; ++r) o[r] = outS[r * 68 + lane];
    build_dispatch<0>(wv, o, rowp);
  }
  __syncthreads();   // barrier 2: upS half0 ready

  f16x8 bbuf[2][4];
#pragma unroll
  for (int ni = 0; ni < 4; ++ni)
    bbuf[0][ni] = *(const f16x8*)&upS[(ni * 16 + ml) * UPROW + q * 8];

#pragma unroll
  for (int c = 0; c < 9; ++c) {
    const int cur = c & 1, nxt = cur ^ 1;
    // prefetch next afr (chunks 1..9; chunk 9 = first half1 chunk)
    abuf[nxt][0] = *(const f16x8*)&wf0[(size_t)(c + 1) * 512];
    abuf[nxt][1] = *(const f16x8*)&wf1[(size_t)(c + 1) * 512];
    if (c < 8) {
      const int t0n = (c + 1) * 32;
#pragma unroll
      for (int ni = 0; ni < 4; ++ni)
        bbuf[nxt][ni] = *(const f16x8*)&upS[(ni * 16 + ml) * UPROW + t0n + q * 8];
    }
#pragma unroll
    for (int ni = 0; ni < 4; ++ni) {
      acc[0][ni] = __builtin_amdgcn_mfma_f32_16x16x32_f16(abuf[cur][0], bbuf[cur][ni], acc[0][ni], 0, 0, 0);
      acc[1][ni] = __builtin_amdgcn_mfma_f32_16x16x32_f16(abuf[cur][1], bbuf[cur][ni], acc[1][ni], 0, 0, 0);
    }
  }
  __syncthreads();   // barrier 3: half0 reads done (WAR before overwrite)

  // ---------------- HALF 1: build t[288,544) then chunks c=9..16 ----------
  {
    float o[RCH];
#pragma unroll
    for (int r = 0; r < RCH; ++r) o[r] = outS[r * 68 + lane];
    build_dispatch<1>(wv, o, rowp);
  }
  __syncthreads();   // barrier 4: upS half1 ready
  // abuf[1] holds chunk 9 (prefetched at c==8, in flight across barriers).

#pragma unroll
  for (int ni = 0; ni < 4; ++ni)
    bbuf[0][ni] = *(const f16x8*)&upS[(ni * 16 + ml) * UPROW + q * 8];

#pragma unroll
  for (int cc = 0; cc < 8; ++cc) {
    const int ca = (cc + 1) & 1;       // abuf parity holding chunk 9+cc
    const int cb = cc & 1, nb = cb ^ 1;
    if (cc < 7) {
      abuf[ca ^ 1][0] = *(const f16x8*)&wf0[(size_t)(10 + cc) * 512];
      abuf[ca ^ 1][1] = *(const f16x8*)&wf1[(size_t)(10 + cc) * 512];
      const int t0n = (cc + 1) * 32;
#pragma unroll
      for (int ni = 0; ni < 4; ++ni)
        bbuf[nb][ni] = *(const f16x8*)&upS[(ni * 16 + ml) * UPROW + t0n + q * 8];
    }
#pragma unroll
    for (int ni = 0; ni < 4; ++ni) {
      acc[0][ni] = __builtin_amdgcn_mfma_f32_16x16x32_f16(abuf[ca][0], bbuf[cb][ni], acc[0][ni], 0, 0, 0);
      acc[1][ni] = __builtin_amdgcn_mfma_f32_16x16x32_f16(abuf[ca][1], bbuf[cb][ni], acc[1][ni], 0, 0, 0);
    }
  }

  // ---------------- Epilogue: signed sqrt, dword stores -------------------
#pragma unroll
  for (int mi = 0; mi < 2; ++mi) {
#pragma unroll
    for (int reg = 0; reg < 4; ++reg) {
      const int o = wv * 32 + mi * 16 + q * 4 + reg;
      float* yrow = y + ((size_t)(b * COUT + o)) * HW + p0 + ml;
#pragma unroll
      for (int ni = 0; ni < 4; ++ni) {
        float v = acc[mi][ni][reg];
        float s = sqrtf(fabsf(v) + 1e-6f);
        yrow[ni * 16] = v > 0.0f ? s : (v < 0.0f ? -s : 0.0f);
      }
    }
  }
}

extern "C" void kernel_launch(void* const* d_in, const int* in_sizes, int n_in,
                              void* d_out, int out_size, void* d_ws, size_t ws_size,
                              hipStream_t stream) {
  const float* x         = (const float*)d_in[0];
  const float* w_reduce  = (const float*)d_in[1];
  const float* w_recover = (const float*)d_in[2];
  float* y = (float*)d_out;

  _Float16* w16   = (_Float16*)d_ws;                            // 272*512*2 = 278528 B
  _Float16* wr16h = (_Float16*)((char*)d_ws + 278528);          // 16384 B
  _Float16* wr16l = (_Float16*)((char*)d_ws + 278528 + 16384);  // 16384 B

  convert_kernel<<<WFROWS + 16, 256, 0, stream>>>(w_reduce, w_recover, w16, wr16h, wr16l);
  fused_kernel<<<NB * (HW / 64), 512, 0, stream>>>(x, w16, wr16h, wr16l, y);
}

// Round 3
// 173.492 us; speedup vs baseline: 1.0810x; 1.0179x over previous
//
#include <hip/hip_runtime.h>
#include <hip/hip_bf16.h>
#include <math.h>

// BilinearGate fused. B=8, Cin=256, HW=9216, R=32, TRI=528, Cout=256.
// v4: sched_group_barrier-pinned pipelines (compiler was re-sinking all
// source-level prefetches: VGPR_Count=44 proved it).
// - Phase 1: all 64 strided x loads issued, then sched_barrier(0) hard fence
//   (one latency round); wr16h/l A-frags in 3-slot depth-2 pipeline pinned
//   with per-ch SGB [VMEM 2][VALU 40][MFMA 3].
// - Phase 2: w16 A-stream is half-independent -> single 17-chunk depth-2
//   (3-slot) pipeline; per-chunk SGB [VMEM 2][DS 4][MFMA 8]. B depth-1.
// - UPROW 296 -> 300 (600B stride, gcd(22,32)=2) to halve LDS bank conflicts.
#define HW     9216
#define CIN    256
#define RCH    32
#define NTRI   528
#define COUT   256
#define NB     8
#define WFROWS 272   // 8 wv * 2 mi * 17 c fragment-rows of 512 halfs
#define UPROW  300   // halfs per upS row (288 data + 12 pad) = 600 B

typedef _Float16 f16x8 __attribute__((ext_vector_type(8)));
typedef _Float16 f16x4 __attribute__((ext_vector_type(4)));
typedef float    f32x4 __attribute__((ext_vector_type(4)));

struct TriTab { unsigned char i[544]; unsigned char j[544]; };
constexpr TriTab make_tri() {
  TriTab t{};
  int ii = 0, jj = 0;
  for (int k = 0; k < 544; ++k) {
    if (k < NTRI) {
      t.i[k] = (unsigned char)ii; t.j[k] = (unsigned char)jj;
      if (++jj == 32) { ++ii; jj = ii; }
    } else { t.i[k] = 0; t.j[k] = 0; }
  }
  return t;
}
constexpr TriTab TRI = make_tri();

// Wave TQ (0..7) builds its share of up[p][t] for one half.
// HALF 0: t in [TQ*36, TQ*36+36). HALF 1: t in [288+TQ*32, 288+TQ*32+32).
template<int TQ, int HALF>
__device__ __forceinline__ void build_up(const float (&o)[RCH], _Float16* rowp) {
  constexpr int NG  = HALF ? 8 : 9;
  constexpr int TLB = TQ * (HALF ? 32 : 36);
  constexpr int TB  = HALF ? 288 : 0;
#pragma unroll
  for (int g = 0; g < NG; ++g) {
    f16x4 v;
#pragma unroll
    for (int s = 0; s < 4; ++s) {
      const int tl = TLB + g * 4 + s;
      const int t  = TB + tl;
      float f = (t < NTRI) ? o[TRI.i[t]] * o[TRI.j[t]] : 0.0f;
      v[s] = (_Float16)f;
    }
    *(f16x4*)&rowp[TLB + g * 4] = v;
  }
}

template<int HALF>
__device__ __forceinline__ void build_dispatch(int wv, const float (&o)[RCH],
                                               _Float16* rowp) {
  switch (wv) {
    case 0: build_up<0, HALF>(o, rowp); break;
    case 1: build_up<1, HALF>(o, rowp); break;
    case 2: build_up<2, HALF>(o, rowp); break;
    case 3: build_up<3, HALF>(o, rowp); break;
    case 4: build_up<4, HALF>(o, rowp); break;
    case 5: build_up<5, HALF>(o, rowp); break;
    case 6: build_up<6, HALF>(o, rowp); break;
    default: build_up<7, HALF>(o, rowp); break;
  }
}

// w16 fragment layout: element (((wv*2+mi)*17 + c)*64 + lane)*8 + s holds
// w_recover[o][t] with o = wv*32+mi*16+(lane&15), t = c*32+(lane>>4)*8+s.
__global__ __launch_bounds__(256) void convert_kernel(
    const float* __restrict__ w_reduce, const float* __restrict__ w_recover,
    _Float16* __restrict__ w16, _Float16* __restrict__ wr16h,
    _Float16* __restrict__ wr16l) {
  const int bx = blockIdx.x;
  const int tid = threadIdx.x;
  if (bx < WFROWS) {
    const int wv  = bx / 34;
    const int rem = bx - wv * 34;
    const int mi  = rem / 17;
    const int c   = rem - mi * 17;
    const int lane = tid >> 2;           // 0..63
    const int s0   = (tid & 3) * 2;      // 0,2,4,6
    const int o = wv * 32 + mi * 16 + (lane & 15);
    const int t = c * 32 + (lane >> 4) * 8 + s0;
    float f0 = (t     < NTRI) ? w_recover[(size_t)o * NTRI + t]     : 0.0f;
    float f1 = (t + 1 < NTRI) ? w_recover[(size_t)o * NTRI + t + 1] : 0.0f;
    _Float16* p = &w16[((size_t)bx * 64 + lane) * 8 + s0];
    p[0] = (_Float16)f0;
    p[1] = (_Float16)f1;
  } else {
    int e = (bx - WFROWS) * 512 + tid;
#pragma unroll
    for (int k = 0; k < 2; ++k, e += 256) {
      float f = w_reduce[e];
      _Float16 h = (_Float16)f;
      wr16h[e] = h;
      wr16l[e] = (_Float16)(f - (float)h);
    }
  }
}

__global__ __launch_bounds__(512, 4) void fused_kernel(
    const float* __restrict__ x, const _Float16* __restrict__ w16,
    const _Float16* __restrict__ wr16h, const _Float16* __restrict__ wr16l,
    float* __restrict__ y) {
  __shared__ float outS[RCH * 68];                     // 8.7 KB
  __shared__ __align__(16) _Float16 upS[64 * UPROW];   // 38.4 KB

  const int tid  = threadIdx.x;
  const int bx   = blockIdx.x;          // 1152 = 8 b * 144 px-tiles
  const int b    = bx / 144;
  const int p0   = (bx - b * 144) * 64;
  const int wv   = tid >> 6;
  const int lane = tid & 63;
  const int ml   = lane & 15;
  const int q    = lane >> 4;
  const int mt   = wv >> 2;             // phase-1 out-row half (0..1)
  const int nt   = wv & 3;              // phase-1 px quarter (0..3)

  // ---------------- Phase 1: GEMM1, no LDS, no barriers -------------------
  {
    f32x4 g1acc;
#pragma unroll
    for (int r2 = 0; r2 < 4; ++r2) g1acc[r2] = 0.0f;

    const int abase = (mt * 16 + ml) * CIN + q * 8;
    // A-pipe prologue: ch 0,1 into slots 0,1 (issued first; L2-resident)
    f16x8 pa[3][2];
    pa[0][0] = *(const f16x8*)&wr16h[abase + 0 * 32];
    pa[0][1] = *(const f16x8*)&wr16l[abase + 0 * 32];
    pa[1][0] = *(const f16x8*)&wr16h[abase + 1 * 32];
    pa[1][1] = *(const f16x8*)&wr16l[abase + 1 * 32];

    // ALL 64 strided x loads issued before the fence -> one latency round.
    const float* xb = x + (size_t)b * CIN * HW + p0 + nt * 16 + ml;
    float xv[64];
#pragma unroll
    for (int ch = 0; ch < 8; ++ch)
#pragma unroll
      for (int s = 0; s < 8; ++s)
        xv[ch * 8 + s] = xb[(size_t)(ch * 32 + q * 8 + s) * HW];
    __builtin_amdgcn_sched_barrier(0);   // hard fence: loads cannot sink

#pragma unroll
    for (int ch = 0; ch < 8; ++ch) {
      const int cur = ch % 3;
      if (ch + 2 < 8) {
        const int pf = (ch + 2) % 3;
        pa[pf][0] = *(const f16x8*)&wr16h[abase + (ch + 2) * 32];
        pa[pf][1] = *(const f16x8*)&wr16l[abase + (ch + 2) * 32];
      }
      f16x8 bh, bl;
#pragma unroll
      for (int s = 0; s < 8; ++s) {
        float f = xv[ch * 8 + s];
        _Float16 h = (_Float16)f;
        bh[s] = h;
        bl[s] = (_Float16)(f - (float)h);
      }
      g1acc = __builtin_amdgcn_mfma_f32_16x16x32_f16(pa[cur][0], bh, g1acc, 0, 0, 0);
      g1acc = __builtin_amdgcn_mfma_f32_16x16x32_f16(pa[cur][1], bh, g1acc, 0, 0, 0);
      g1acc = __builtin_amdgcn_mfma_f32_16x16x32_f16(pa[cur][0], bl, g1acc, 0, 0, 0);
      if (ch + 2 < 8)
        __builtin_amdgcn_sched_group_barrier(0x020, 2, 0);   // A prefetch
      __builtin_amdgcn_sched_group_barrier(0x002, 40, 0);    // conversion VALU
      __builtin_amdgcn_sched_group_barrier(0x008, 3, 0);     // MFMAs
    }
    // D[row=q*4+reg][col=ml]: r = mt*16+q*4+reg, p = nt*16+ml
#pragma unroll
    for (int reg = 0; reg < 4; ++reg)
      outS[(mt * 16 + q * 4 + reg) * 68 + nt * 16 + ml] = g1acc[reg];
  }

  // Fragment bases into pre-swizzled w16 (chunk c at +c*512 halfs).
  const _Float16* wf0 = w16 + ((size_t)(wv * 2 + 0) * 17 * 64 + lane) * 8;
  const _Float16* wf1 = w16 + ((size_t)(wv * 2 + 1) * 17 * 64 + lane) * 8;

  // A-stream depth-2 prologue: chunks 0,1 issued BEFORE the barriers.
  f16x8 abuf[3][2];
  abuf[0][0] = *(const f16x8*)&wf0[0];
  abuf[0][1] = *(const f16x8*)&wf1[0];
  abuf[1][0] = *(const f16x8*)&wf0[512];
  abuf[1][1] = *(const f16x8*)&wf1[512];

  __syncthreads();   // barrier 1: outS complete

  f32x4 acc[2][4];
#pragma unroll
  for (int mi = 0; mi < 2; ++mi)
#pragma unroll
    for (int ni = 0; ni < 4; ++ni)
#pragma unroll
      for (int r2 = 0; r2 < 4; ++r2) acc[mi][ni][r2] = 0.0f;

  _Float16* rowp = &upS[lane * UPROW];

  // ---------------- HALF 0: build t[0,288) then chunks c=0..8 -------------
  {
    float o[RCH];
#pragma unroll
    for (int r = 0; r < RCH; ++r) o[r] = outS[r * 68 + lane];
    build_dispatch<0>(wv, o, rowp);
  }
  __syncthreads();   // barrier 2: upS half0 ready

  f16x8 bbuf[2][4];
#pragma unroll
  for (int ni = 0; ni < 4; ++ni)
    bbuf[0][ni] = *(const f16x8*)&upS[(ni * 16 + ml) * UPROW + q * 8];

#pragma unroll
  for (int c = 0; c < 9; ++c) {
    const int cur = c % 3;
    const int pf  = (c + 2) % 3;     // chunks c+2 <= 10 < 17: always valid
    abuf[pf][0] = *(const f16x8*)&wf0[(size_t)(c + 2) * 512];
    abuf[pf][1] = *(const f16x8*)&wf1[(size_t)(c + 2) * 512];
    const int cb = c & 1, nb = cb ^ 1;
    if (c < 8) {
      const int t0n = (c + 1) * 32;
#pragma unroll
      for (int ni = 0; ni < 4; ++ni)
        bbuf[nb][ni] = *(const f16x8*)&upS[(ni * 16 + ml) * UPROW + t0n + q * 8];
    }
#pragma unroll
    for (int ni = 0; ni < 4; ++ni) {
      acc[0][ni] = __builtin_amdgcn_mfma_f32_16x16x32_f16(abuf[cur][0], bbuf[cb][ni], acc[0][ni], 0, 0, 0);
      acc[1][ni] = __builtin_amdgcn_mfma_f32_16x16x32_f16(abuf[cur][1], bbuf[cb][ni], acc[1][ni], 0, 0, 0);
    }
    __builtin_amdgcn_sched_group_barrier(0x020, 2, 0);     // A prefetch
    if (c < 8)
      __builtin_amdgcn_sched_group_barrier(0x100, 4, 0);   // B ds_reads
    __builtin_amdgcn_sched_group_barrier(0x008, 8, 0);     // MFMAs
  }
  __syncthreads();   // barrier 3: half0 reads done (WAR before overwrite)

  // ---------------- HALF 1: build t[288,544) then chunks g=9..16 ----------
  {
    float o[RCH];
#pragma unroll
    for (int r = 0; r < RCH; ++r) o[r] = outS[r * 68 + lane];
    build_dispatch<1>(wv, o, rowp);
  }
  __syncthreads();   // barrier 4: upS half1 ready
  // abuf slots hold chunk 9 (slot 0) and 10 (slot 1), in flight across barriers.

#pragma unroll
  for (int ni = 0; ni < 4; ++ni)
    bbuf[0][ni] = *(const f16x8*)&upS[(ni * 16 + ml) * UPROW + q * 8];

#pragma unroll
  for (int cc = 0; cc < 8; ++cc) {
    const int cur = cc % 3;          // global chunk g=9+cc, (9+cc)%3 == cc%3
    if (cc < 6) {
      const int pf = (2 + cc) % 3;   // chunk 11+cc, valid while 11+cc <= 16
      abuf[pf][0] = *(const f16x8*)&wf0[(size_t)(11 + cc) * 512];
      abuf[pf][1] = *(const f16x8*)&wf1[(size_t)(11 + cc) * 512];
    }
    const int cb = cc & 1, nb = cb ^ 1;
    if (cc < 7) {
      const int t0n = (cc + 1) * 32;
#pragma unroll
      for (int ni = 0; ni < 4; ++ni)
        bbuf[nb][ni] = *(const f16x8*)&upS[(ni * 16 + ml) * UPROW + t0n + q * 8];
    }
#pragma unroll
    for (int ni = 0; ni < 4; ++ni) {
      acc[0][ni] = __builtin_amdgcn_mfma_f32_16x16x32_f16(abuf[cur][0], bbuf[cb][ni], acc[0][ni], 0, 0, 0);
      acc[1][ni] = __builtin_amdgcn_mfma_f32_16x16x32_f16(abuf[cur][1], bbuf[cb][ni], acc[1][ni], 0, 0, 0);
    }
    if (cc < 6)
      __builtin_amdgcn_sched_group_barrier(0x020, 2, 0);   // A prefetch
    if (cc < 7)
      __builtin_amdgcn_sched_group_barrier(0x100, 4, 0);   // B ds_reads
    __builtin_amdgcn_sched_group_barrier(0x008, 8, 0);     // MFMAs
  }

  // ---------------- Epilogue: signed sqrt, dword stores -------------------
#pragma unroll
  for (int mi = 0; mi < 2; ++mi) {
#pragma unroll
    for (int reg = 0; reg < 4; ++reg) {
      const int o = wv * 32 + mi * 16 + q * 4 + reg;
      float* yrow = y + ((size_t)(b * COUT + o)) * HW + p0 + ml;
#pragma unroll
      for (int ni = 0; ni < 4; ++ni) {
        float v = acc[mi][ni][reg];
        float s = sqrtf(fabsf(v) + 1e-6f);
        yrow[ni * 16] = v > 0.0f ? s : (v < 0.0f ? -s : 0.0f);
      }
    }
  }
}

extern "C" void kernel_launch(void* const* d_in, const int* in_sizes, int n_in,
                              void* d_out, int out_size, void* d_ws, size_t ws_size,
                              hipStream_t stream) {
  const float* x         = (const float*)d_in[0];
  const float* w_reduce  = (const float*)d_in[1];
  const float* w_recover = (const float*)d_in[2];
  float* y = (float*)d_out;

  _Float16* w16   = (_Float16*)d_ws;                            // 272*512*2 = 278528 B
  _Float16* wr16h = (_Float16*)((char*)d_ws + 278528);          // 16384 B
  _Float16* wr16l = (_Float16*)((char*)d_ws + 278528 + 16384);  // 16384 B

  convert_kernel<<<WFROWS + 16, 256, 0, stream>>>(w_reduce, w_recover, w16, wr16h, wr16l);
  fused_kernel<<<NB * (HW / 64), 512, 0, stream>>>(x, w16, wr16h, wr16l, y);
}